// Round 10
// baseline (197.110 us; speedup 1.0000x reference)
//
#include <hip/hip_runtime.h>
#include <math.h>

#define NCL 21
#define CIN 256
#define HW 4096
#define PADK 24
#define NB 2

static __device__ __forceinline__ float fastrcp(float x) {
  return __builtin_amdgcn_rcpf(x);
}

// ---------------------------------------------------------------------------
// Kernel A: f1/f2 = 1x1 conv (w @ feat + b). f1 rows are PRE-SCALED by
// 1/sqrt(21) (all three consumers -- stats, corr, norm -- multiply the dot by
// SCALE, so fold it into f1 once). Block = 16 q x 16 c-chunks; LDS reduction.
#define QT 16
#define CCH 16
__global__ __launch_bounds__(256) void k_feat(
    const float* __restrict__ feat, const float* __restrict__ w1,
    const float* __restrict__ b1, const float* __restrict__ w2,
    const float* __restrict__ b2, float* __restrict__ f1T,
    float* __restrict__ f2) {
  const int t = threadIdx.x;
  const int qi = t & 15, ch = t >> 4;  // 16 chunks of 16 channels
  const int n = blockIdx.y;
  const int q = blockIdx.x * QT + qi;
  const int c0 = ch * CCH;
  const float* fp = feat + ((size_t)n * CIN + c0) * HW + q;
  float a1[NCL], a2[NCL];
#pragma unroll
  for (int k = 0; k < NCL; ++k) { a1[k] = 0.f; a2[k] = 0.f; }
#pragma unroll
  for (int cc = 0; cc < CCH; ++cc) {
    float v = fp[(size_t)cc * HW];
#pragma unroll
    for (int k = 0; k < NCL; ++k) {  // w reads thread-uniform -> s_load
      a1[k] = fmaf(v, w1[k * CIN + c0 + cc], a1[k]);
      a2[k] = fmaf(v, w2[k * CIN + c0 + cc], a2[k]);
    }
  }
  __shared__ float p1[CCH][QT][NCL];
  __shared__ float p2[CCH][QT][NCL];
#pragma unroll
  for (int k = 0; k < NCL; ++k) { p1[ch][qi][k] = a1[k]; p2[ch][qi][k] = a2[k]; }
  __syncthreads();
  const float SCALE = 1.0f / sqrtf(21.0f);
  for (int o = t; o < QT * NCL; o += 256) {
    int qq = o & 15, k = o >> 4;
    float s1 = b1[k], s2 = b2[k];
#pragma unroll
    for (int c = 0; c < CCH; ++c) { s1 += p1[c][qq][k]; s2 += p2[c][qq][k]; }
    int qg = blockIdx.x * QT + qq;
    f1T[((size_t)n * HW + qg) * PADK + k] = s1 * SCALE;  // pre-scaled
    f2[((size_t)n * NCL + k) * HW + qg] = s2;
  }
}

// ---------------------------------------------------------------------------
// Kernel C (fused, v4): per block = (8 p-rows, n), all 4096 q in-block, then
// the k_outr epilogue for the same 8 p. R8 lesson: capping VGPR by decree
// spills catastrophically; q=2 (float2) cut the live set structurally ->
// VGPR <= 128, dropped out of top-5 in R9.
#define PT 8
__global__ __launch_bounds__(256) void k_statsoutr(
    const float* __restrict__ f1T, const float* __restrict__ f2,
    const float* __restrict__ out, float* __restrict__ otT) {
  __shared__ float srow[PT * PADK];  // 8 rows * 24 floats = 768 B
  __shared__ float red[4][PT];
  __shared__ float linv[PT];
  const int t = threadIdx.x;
  const int n = blockIdx.y;
  const int pbase = blockIdx.x * PT;
  if (t < PT * PADK / 4) {
    ((float4*)srow)[t] =
        ((const float4*)(f1T + ((size_t)n * HW + pbase) * PADK))[t];
  }
  __syncthreads();
  const float* f2n = f2 + (size_t)n * NCL * HW;
  float sums[PT];
#pragma unroll
  for (int p = 0; p < PT; ++p) sums[p] = 0.f;
  for (int qc = 0; qc < 8; ++qc) {
    const int q0 = qc * 512 + t * 2;
    float2 dp[PT];  // dot partials: 16 VGPR
#pragma unroll
    for (int p = 0; p < PT; ++p) dp[p] = make_float2(0.f, 0.f);
#pragma unroll
    for (int g = 0; g < 5; ++g) {  // k = 4g .. 4g+3
      float2 fg0 = *(const float2*)(f2n + (size_t)(4 * g + 0) * HW + q0);
      float2 fg1 = *(const float2*)(f2n + (size_t)(4 * g + 1) * HW + q0);
      float2 fg2 = *(const float2*)(f2n + (size_t)(4 * g + 2) * HW + q0);
      float2 fg3 = *(const float2*)(f2n + (size_t)(4 * g + 3) * HW + q0);
#pragma unroll
      for (int p = 0; p < PT; ++p) {
        float4 ag = *(const float4*)(srow + p * PADK + 4 * g);
        dp[p].x = fmaf(ag.x, fg0.x, dp[p].x);
        dp[p].y = fmaf(ag.x, fg0.y, dp[p].y);
        dp[p].x = fmaf(ag.y, fg1.x, dp[p].x);
        dp[p].y = fmaf(ag.y, fg1.y, dp[p].y);
        dp[p].x = fmaf(ag.z, fg2.x, dp[p].x);
        dp[p].y = fmaf(ag.z, fg2.y, dp[p].y);
        dp[p].x = fmaf(ag.w, fg3.x, dp[p].x);
        dp[p].y = fmaf(ag.w, fg3.y, dp[p].y);
      }
    }
    {  // k = 20 tail
      float2 f20 = *(const float2*)(f2n + (size_t)20 * HW + q0);
#pragma unroll
      for (int p = 0; p < PT; ++p) {
        float a20 = srow[p * PADK + 20];
        dp[p].x = fmaf(a20, f20.x, dp[p].x);
        dp[p].y = fmaf(a20, f20.y, dp[p].y);
      }
    }
#pragma unroll
    for (int p = 0; p < PT; ++p)
      sums[p] += __expf(dp[p].x) + __expf(dp[p].y);
  }
  const int wave = t >> 6, lane = t & 63;
#pragma unroll
  for (int p = 0; p < PT; ++p) {
    float s = sums[p];
    for (int off = 32; off > 0; off >>= 1) s += __shfl_xor(s, off, 64);
    if (lane == 0) red[wave][p] = s;
  }
  __syncthreads();
  if (t < PT) {
    float tot = red[0][t] + red[1][t] + red[2][t] + red[3][t];
    linv[t] = fastrcp(tot);
  }
  __syncthreads();
  // k_outr epilogue for the 8 p of this block: 8*21 = 168 outputs.
  for (int o = t; o < PT * NCL; o += 256) {
    int pl = o & 7, c = o >> 3;
    int pg = pbase + pl;
    int i = pg >> 6, j = pg & 63;
    double sy = (double)i * (127.0 / 63.0);
    double sx = (double)j * (127.0 / 63.0);
    int y0 = (int)sy, x0 = (int)sx;
    float wy = (float)(sy - y0), wx = (float)(sx - x0);
    int y1 = min(y0 + 1, 127), x1 = min(x0 + 1, 127);
    const float* src = out + ((size_t)n * NCL + c) * (128 * 128);
    float v00 = src[y0 * 128 + x0], v10 = src[y1 * 128 + x0];
    float v01 = src[y0 * 128 + x1], v11 = src[y1 * 128 + x1];
    float r0 = v00 * (1.f - wy) + v10 * wy;
    float r1 = v01 * (1.f - wy) + v11 * wy;
    float val = r0 * (1.f - wx) + r1 * wx;
    otT[((size_t)n * HW + pg) * PADK + c] = val * linv[pl];
  }
}

// ---------------------------------------------------------------------------
// Kernel D (v9): residency-doubled geometry. R9 measured k_corr8 at VGPR
// EXACTLY 128 (4 waves/SIMD allowed; the halving cliff is at >128 -- R6's
// 132 proved it) with VALUBusy 65% at 46 us: the GRID (512 blocks = 2/CU)
// was the binding constraint, not the machine caps. Q=4 is frozen (Q=2
// doubles the broadcast-ds pipe to ~50 us/CU, R3 calibration), so blocks
// must come from a finer p-split. PSPLIT must divide 4096 (ragged DPS costs
// +4 VGPR -> 132 -> cliff, R6-vs-R9 A/B), so PSPLIT=32 / DPS=128: grid
// 16x32x2 = 1024 = EXACTLY 4 blocks/CU, one round, zero tail; LDS 24.6 KB
// x4 = 98 KB and VGPR 128 x16 waves = 2048 -- both caps exactly saturated.
// The 32 slabs (22 MB) move to the WORKSPACE, guarded by ws_size; if ws is
// too small we fall back to the R9-proven PSPLIT=16/out0 config.
template <int DPS>
__global__ __launch_bounds__(256) void k_corr9(
    const float* __restrict__ f1T, const float* __restrict__ f2,
    const float* __restrict__ otT, float* __restrict__ part) {
  __shared__ float smem[2 * DPS * PADK];
  float* sf1 = smem;
  float* sot = smem + DPS * PADK;
  const int t = threadIdx.x;  // 0..255
  const int lane = t & 63, wid = t >> 6;
  const int n = blockIdx.z, pb = blockIdx.y;
  const int pbase = pb * DPS;
  {
    const float4* gf = (const float4*)(f1T + ((size_t)n * HW + pbase) * PADK);
    const float4* go = (const float4*)(otT + ((size_t)n * HW + pbase) * PADK);
    float4* sa = (float4*)sf1;
    float4* sb = (float4*)sot;
#pragma unroll
    for (int i = 0; i < DPS * (PADK / 4) / 256; ++i) {
      sa[t + i * 256] = gf[t + i * 256];
      sb[t + i * 256] = go[t + i * 256];
    }
  }
  __syncthreads();
  const int q = blockIdx.x * 256 + lane * 4;
  const float* f2n = f2 + (size_t)n * NCL * HW;
  float4 fq[NCL];
#pragma unroll
  for (int k = 0; k < NCL; ++k)
    fq[k] = *(const float4*)(f2n + (size_t)k * HW + q);
  float4 acc[NCL];
#pragma unroll
  for (int k = 0; k < NCL; ++k) acc[k] = make_float4(0.f, 0.f, 0.f, 0.f);
  const int plo = wid * (DPS / 4);
  const int phi = plo + (DPS / 4);
#pragma unroll 2
  for (int p = plo; p < phi; ++p) {
    const float4* r1 = (const float4*)(sf1 + p * PADK);
    float a[NCL];
    *(float4*)(a + 0) = r1[0];
    *(float4*)(a + 4) = r1[1];
    *(float4*)(a + 8) = r1[2];
    *(float4*)(a + 12) = r1[3];
    *(float4*)(a + 16) = r1[4];
    a[20] = ((const float*)r1)[20];
    float d0 = 0.f, d1 = 0.f, d2 = 0.f, d3 = 0.f;  // 4 independent chains
#pragma unroll
    for (int k = 0; k < NCL; ++k) {
      d0 = fmaf(a[k], fq[k].x, d0);
      d1 = fmaf(a[k], fq[k].y, d1);
      d2 = fmaf(a[k], fq[k].z, d2);
      d3 = fmaf(a[k], fq[k].w, d3);
    }
    float w0 = __expf(d0), w1 = __expf(d1), w2 = __expf(d2), w3 = __expf(d3);
    const float4* ro = (const float4*)(sot + p * PADK);
    float o[NCL];
    *(float4*)(o + 0) = ro[0];
    *(float4*)(o + 4) = ro[1];
    *(float4*)(o + 8) = ro[2];
    *(float4*)(o + 12) = ro[3];
    *(float4*)(o + 16) = ro[4];
    o[20] = ((const float*)ro)[20];
#pragma unroll
    for (int k = 0; k < NCL; ++k) {
      acc[k].x = fmaf(o[k], w0, acc[k].x);
      acc[k].y = fmaf(o[k], w1, acc[k].y);
      acc[k].z = fmaf(o[k], w2, acc[k].z);
      acc[k].w = fmaf(o[k], w3, acc[k].w);
    }
  }
  // 3-round ping-pong combine through the (now dead) LDS tile: one wave's
  // acc = 21*64 float4 = 5.4 KB <= buffer.
  __syncthreads();  // all ds reads of sf1/sot done; safe to reuse smem
  float4* sbuf = (float4*)smem;
  if (wid == 1) {
#pragma unroll
    for (int c = 0; c < NCL; ++c) sbuf[c * 64 + lane] = acc[c];
  }
  __syncthreads();
  if (wid == 0) {
#pragma unroll
    for (int c = 0; c < NCL; ++c) {
      float4 v = sbuf[c * 64 + lane];
      acc[c].x += v.x; acc[c].y += v.y; acc[c].z += v.z; acc[c].w += v.w;
    }
  }
  __syncthreads();
  if (wid == 3) {
#pragma unroll
    for (int c = 0; c < NCL; ++c) sbuf[c * 64 + lane] = acc[c];
  }
  __syncthreads();
  if (wid == 2) {
#pragma unroll
    for (int c = 0; c < NCL; ++c) {
      float4 v = sbuf[c * 64 + lane];
      acc[c].x += v.x; acc[c].y += v.y; acc[c].z += v.z; acc[c].w += v.w;
    }
  }
  __syncthreads();
  if (wid == 2) {
#pragma unroll
    for (int c = 0; c < NCL; ++c) sbuf[c * 64 + lane] = acc[c];
  }
  __syncthreads();
  if (wid == 0) {
    float* po = part + ((size_t)pb * NB + n) * NCL * HW + q;
#pragma unroll
    for (int c = 0; c < NCL; ++c) {
      float4 v = sbuf[c * 64 + lane];
      v.x += acc[c].x; v.y += acc[c].y; v.z += acc[c].z; v.w += acc[c].w;
      *(float4*)(po + (size_t)c * HW) = v;
    }
  }
}

// ---------------------------------------------------------------------------
// Kernel D2: corr_out[idx] = sum over the PS partial slabs. 672 blocks,
// fully coalesced strided reads; replaces the corr_out memset too.
template <int PS>
__global__ __launch_bounds__(256) void k_reduce(
    const float* __restrict__ part, float* __restrict__ corr_out) {
  const int idx = blockIdx.x * 256 + threadIdx.x;  // NB*NCL*HW = 672*256
  const float* p = part + idx;
  float s = 0.f;
#pragma unroll
  for (int pb = 0; pb < PS; ++pb)
    s += p[(size_t)pb * (NB * NCL * HW)];
  corr_out[idx] = s;
}

// ---------------------------------------------------------------------------
// Kernel E (fused): per sampled row (i, n): compute the unnormalized exp-row
// straight into LDS (min/max normalization is invariant to the softmax
// denominator), bilinear tables in-block, upsample 64->128, min/max
// normalize, write >0.5 booleans as 1.0/0.0.
__global__ __launch_bounds__(256) void k_norm(
    const float* __restrict__ f1T, const float* __restrict__ f2,
    const int* __restrict__ index, float* __restrict__ out0) {
  __shared__ float row[HW];
  __shared__ float redmn[4], redmx[4];
  __shared__ float wt[128];
  __shared__ int it[128];
  const int t = threadIdx.x;
  const int i = blockIdx.x;
  const int n = blockIdx.y;
  if (t < 128) {
    double s = (double)t * (63.0 / 127.0);
    int i0 = (int)s;
    wt[t] = (float)(s - i0);
    it[t] = i0;
  }
  int p = index[i];
  p = max(0, min(p, HW - 1));
  const float* f1p = f1T + ((size_t)n * HW + p) * PADK;
  float a[NCL];
#pragma unroll
  for (int k = 0; k < NCL; ++k) a[k] = f1p[k];
  const float* f2n = f2 + (size_t)n * NCL * HW;
  for (int qc = 0; qc < 4; ++qc) {
    const int q0 = qc * 1024 + t * 4;
    float d0 = 0.f, d1 = 0.f, d2 = 0.f, d3 = 0.f;
#pragma unroll
    for (int k = 0; k < NCL; ++k) {
      float4 f = *(const float4*)(f2n + (size_t)k * HW + q0);
      d0 = fmaf(a[k], f.x, d0);
      d1 = fmaf(a[k], f.y, d1);
      d2 = fmaf(a[k], f.z, d2);
      d3 = fmaf(a[k], f.w, d3);
    }
    *(float4*)(row + q0) =
        make_float4(__expf(d0), __expf(d1), __expf(d2), __expf(d3));
  }
  __syncthreads();
  float vv[64];
  float lmn = 1e30f, lmx = -1e30f;
  for (int j = 0; j < 64; ++j) {
    int pix = t + j * 256;
    int yy = pix >> 7, xx = pix & 127;
    int y0 = it[yy], x0 = it[xx];
    float wy = wt[yy], wx = wt[xx];
    int y1 = min(y0 + 1, 63), x1 = min(x0 + 1, 63);
    float r0 = row[y0 * 64 + x0] * (1.f - wy) + row[y1 * 64 + x0] * wy;
    float r1 = row[y0 * 64 + x1] * (1.f - wy) + row[y1 * 64 + x1] * wy;
    float v = r0 * (1.f - wx) + r1 * wx;
    vv[j] = v;
    lmn = fminf(lmn, v);
    lmx = fmaxf(lmx, v);
  }
  for (int off = 32; off > 0; off >>= 1) {
    lmn = fminf(lmn, __shfl_xor(lmn, off, 64));
    lmx = fmaxf(lmx, __shfl_xor(lmx, off, 64));
  }
  const int wave = t >> 6, lane = t & 63;
  if (lane == 0) { redmn[wave] = lmn; redmx[wave] = lmx; }
  __syncthreads();
  float mn = fminf(fminf(redmn[0], redmn[1]), fminf(redmn[2], redmn[3]));
  float mx = fmaxf(fmaxf(redmx[0], redmx[1]), fmaxf(redmx[2], redmx[3]));
  float rng = mx - mn;
  float* slot = out0 + ((size_t)n * 128 + i) * (128 * 128);
  for (int j = 0; j < 64; ++j) {
    int pix = t + j * 256;
    float nrm = (vv[j] - mn) / rng;
    slot[pix] = (nrm > 0.5f) ? 1.0f : 0.0f;
  }
}

// ---------------------------------------------------------------------------
extern "C" void kernel_launch(void* const* d_in, const int* in_sizes, int n_in,
                              void* d_out, int out_size, void* d_ws,
                              size_t ws_size, hipStream_t stream) {
  (void)in_sizes; (void)n_in; (void)out_size;
  const float* feat = (const float*)d_in[0];
  const float* out  = (const float*)d_in[1];
  const float* w1   = (const float*)d_in[2];
  const float* b1   = (const float*)d_in[3];
  const float* w2   = (const float*)d_in[4];
  const float* b2   = (const float*)d_in[5];
  const int* index  = (const int*)d_in[6];

  float* ws   = (float*)d_ws;
  float* f1T  = ws;                                   // 2*4096*24 = 196608
  float* f2   = ws + 196608;                          // 2*21*4096 = 172032
  float* otT  = ws + 196608 + 172032;                 // 196608
  const size_t ws_base = 196608 + 172032 + 196608;    // 565248 floats

  float* out0     = (float*)d_out;                    // 2*128*128*128
  float* corr_out = out0 + (size_t)NB * 128 * 128 * 128;  // 2*21*4096

  k_feat<<<dim3(HW / QT, 2), 256, 0, stream>>>(feat, w1, b1, w2, b2, f1T, f2);
  k_statsoutr<<<dim3(HW / PT, 2), 256, 0, stream>>>(f1T, f2, out, otT);

  // Preferred: 32 slabs (22 MB) in workspace -> 1024-block single-round grid.
  const size_t need = (ws_base + 32ull * NB * NCL * HW) * sizeof(float);
  if (ws_size >= need) {
    float* part = ws + ws_base;
    k_corr9<128><<<dim3(16, 32, 2), 256, 0, stream>>>(f1T, f2, otT, part);
    k_reduce<32><<<dim3(672), 256, 0, stream>>>(part, corr_out);
  } else {
    // Fallback (R9-proven): 16 slabs (10.8 MB) parked in the out0 region,
    // consumed by k_reduce before k_norm writes out0 (same-stream ordering).
    float* part = out0;
    k_corr9<256><<<dim3(16, 16, 2), 256, 0, stream>>>(f1T, f2, otT, part);
    k_reduce<16><<<dim3(672), 256, 0, stream>>>(part, corr_out);
  }
  k_norm<<<dim3(128, 2), 256, 0, stream>>>(f1T, f2, index, out0);
}

// Round 11
// 188.098 us; speedup vs baseline: 1.0479x; 1.0479x over previous
//
#include <hip/hip_runtime.h>
#include <math.h>

#define NCL 21
#define CIN 256
#define HW 4096
#define PADK 24
#define NB 2

static __device__ __forceinline__ float fastrcp(float x) {
  return __builtin_amdgcn_rcpf(x);
}

// ---------------------------------------------------------------------------
// Kernel A: f1/f2 = 1x1 conv (w @ feat + b). f1 rows are PRE-SCALED by
// 1/sqrt(21) (all three consumers -- stats, corr, norm -- multiply the dot by
// SCALE, so fold it into f1 once). Block = 16 q x 16 c-chunks; LDS reduction.
#define QT 16
#define CCH 16
__global__ __launch_bounds__(256) void k_feat(
    const float* __restrict__ feat, const float* __restrict__ w1,
    const float* __restrict__ b1, const float* __restrict__ w2,
    const float* __restrict__ b2, float* __restrict__ f1T,
    float* __restrict__ f2) {
  const int t = threadIdx.x;
  const int qi = t & 15, ch = t >> 4;  // 16 chunks of 16 channels
  const int n = blockIdx.y;
  const int q = blockIdx.x * QT + qi;
  const int c0 = ch * CCH;
  const float* fp = feat + ((size_t)n * CIN + c0) * HW + q;
  float a1[NCL], a2[NCL];
#pragma unroll
  for (int k = 0; k < NCL; ++k) { a1[k] = 0.f; a2[k] = 0.f; }
#pragma unroll
  for (int cc = 0; cc < CCH; ++cc) {
    float v = fp[(size_t)cc * HW];
#pragma unroll
    for (int k = 0; k < NCL; ++k) {  // w reads thread-uniform -> s_load
      a1[k] = fmaf(v, w1[k * CIN + c0 + cc], a1[k]);
      a2[k] = fmaf(v, w2[k * CIN + c0 + cc], a2[k]);
    }
  }
  __shared__ float p1[CCH][QT][NCL];
  __shared__ float p2[CCH][QT][NCL];
#pragma unroll
  for (int k = 0; k < NCL; ++k) { p1[ch][qi][k] = a1[k]; p2[ch][qi][k] = a2[k]; }
  __syncthreads();
  const float SCALE = 1.0f / sqrtf(21.0f);
  for (int o = t; o < QT * NCL; o += 256) {
    int qq = o & 15, k = o >> 4;
    float s1 = b1[k], s2 = b2[k];
#pragma unroll
    for (int c = 0; c < CCH; ++c) { s1 += p1[c][qq][k]; s2 += p2[c][qq][k]; }
    int qg = blockIdx.x * QT + qq;
    f1T[((size_t)n * HW + qg) * PADK + k] = s1 * SCALE;  // pre-scaled
    f2[((size_t)n * NCL + k) * HW + qg] = s2;
  }
}

// ---------------------------------------------------------------------------
// Kernel C (fused, v5): per block = (8 p-rows, n), all 4096 q in-block, then
// the k_outr epilogue for the same 8 p. History: v2 (q=4, k-group 4) hit the
// VGPR cliff at 132 (R7, 48.6 us); v4 (q=2) fit <=128 but doubled the
// broadcast-ds pipe to 384 b128/wave ~= 31 us/CU -- LDS-issue-bound like
// R3's corr. v5 restores q=4 (float4) but shrinks the k-step to 2: only
// fa/fb (8 VGPR) in flight instead of 16, and srow reads become ds_read_b64
// (~7 cyc vs 12). ds/wave: 352 b64 ~= 2.5K cyc (4x less LDS time than v4);
// qc back to 4 -> f2 L2 traffic unchanged; FMA count unchanged. Live set
// dp[8]xfloat4(32)+fa/fb(8)+sums(8)+addr ~= 70 -> VGPR ~100 < 128 cliff.
// Grid 1024 = 4 blocks/CU, one scheduling round.
#define PT 8
__global__ __launch_bounds__(256) void k_statsoutr(
    const float* __restrict__ f1T, const float* __restrict__ f2,
    const float* __restrict__ out, float* __restrict__ otT) {
  __shared__ float srow[PT * PADK];  // 8 rows * 24 floats = 768 B
  __shared__ float red[4][PT];
  __shared__ float linv[PT];
  const int t = threadIdx.x;
  const int n = blockIdx.y;
  const int pbase = blockIdx.x * PT;
  if (t < PT * PADK / 4) {
    ((float4*)srow)[t] =
        ((const float4*)(f1T + ((size_t)n * HW + pbase) * PADK))[t];
  }
  __syncthreads();
  const float* f2n = f2 + (size_t)n * NCL * HW;
  float sums[PT];
#pragma unroll
  for (int p = 0; p < PT; ++p) sums[p] = 0.f;
  for (int qc = 0; qc < 4; ++qc) {
    const int q0 = qc * 1024 + t * 4;
    float4 dp[PT];  // dot partials: 32 VGPR
#pragma unroll
    for (int p = 0; p < PT; ++p) dp[p] = make_float4(0.f, 0.f, 0.f, 0.f);
#pragma unroll
    for (int g = 0; g < 10; ++g) {  // k = 2g, 2g+1
      float4 fa = *(const float4*)(f2n + (size_t)(2 * g) * HW + q0);
      float4 fb = *(const float4*)(f2n + (size_t)(2 * g + 1) * HW + q0);
#pragma unroll
      for (int p = 0; p < PT; ++p) {
        float2 ag = *(const float2*)(srow + p * PADK + 2 * g);  // ds_read_b64
        dp[p].x = fmaf(ag.x, fa.x, dp[p].x);
        dp[p].y = fmaf(ag.x, fa.y, dp[p].y);
        dp[p].z = fmaf(ag.x, fa.z, dp[p].z);
        dp[p].w = fmaf(ag.x, fa.w, dp[p].w);
        dp[p].x = fmaf(ag.y, fb.x, dp[p].x);
        dp[p].y = fmaf(ag.y, fb.y, dp[p].y);
        dp[p].z = fmaf(ag.y, fb.z, dp[p].z);
        dp[p].w = fmaf(ag.y, fb.w, dp[p].w);
      }
    }
    {  // k = 20 tail
      float4 f20 = *(const float4*)(f2n + (size_t)20 * HW + q0);
#pragma unroll
      for (int p = 0; p < PT; ++p) {
        float a20 = srow[p * PADK + 20];
        dp[p].x = fmaf(a20, f20.x, dp[p].x);
        dp[p].y = fmaf(a20, f20.y, dp[p].y);
        dp[p].z = fmaf(a20, f20.z, dp[p].z);
        dp[p].w = fmaf(a20, f20.w, dp[p].w);
      }
    }
#pragma unroll
    for (int p = 0; p < PT; ++p)
      sums[p] += __expf(dp[p].x) + __expf(dp[p].y) + __expf(dp[p].z) +
                 __expf(dp[p].w);
  }
  const int wave = t >> 6, lane = t & 63;
#pragma unroll
  for (int p = 0; p < PT; ++p) {
    float s = sums[p];
    for (int off = 32; off > 0; off >>= 1) s += __shfl_xor(s, off, 64);
    if (lane == 0) red[wave][p] = s;
  }
  __syncthreads();
  if (t < PT) {
    float tot = red[0][t] + red[1][t] + red[2][t] + red[3][t];
    linv[t] = fastrcp(tot);
  }
  __syncthreads();
  // k_outr epilogue for the 8 p of this block: 8*21 = 168 outputs.
  for (int o = t; o < PT * NCL; o += 256) {
    int pl = o & 7, c = o >> 3;
    int pg = pbase + pl;
    int i = pg >> 6, j = pg & 63;
    double sy = (double)i * (127.0 / 63.0);
    double sx = (double)j * (127.0 / 63.0);
    int y0 = (int)sy, x0 = (int)sx;
    float wy = (float)(sy - y0), wx = (float)(sx - x0);
    int y1 = min(y0 + 1, 127), x1 = min(x0 + 1, 127);
    const float* src = out + ((size_t)n * NCL + c) * (128 * 128);
    float v00 = src[y0 * 128 + x0], v10 = src[y1 * 128 + x0];
    float v01 = src[y0 * 128 + x1], v11 = src[y1 * 128 + x1];
    float r0 = v00 * (1.f - wy) + v10 * wy;
    float r1 = v01 * (1.f - wy) + v11 * wy;
    float val = r0 * (1.f - wx) + r1 * wx;
    otT[((size_t)n * HW + pg) * PADK + c] = val * linv[pl];
  }
}

// ---------------------------------------------------------------------------
// Kernel D (v8, R9-proven config restored): R10 established that the Q=4
// loop's TRUE live set is ~168 regs (arch-VGPR 128 + AGPR balance on the
// gfx950 unified file) -> real cap ~3 waves/SIMD. A 1024-block grid (DPS=128)
// needs 4 blocks/CU, gets 3 -> 1.33 scheduling rounds -> 71 us (R10). There
// is no clean 3-blocks/CU grid (768 = ragged DPS, +VGPR risk per R6), and
// Q=2 doubles the ds pipe to ~60 us (R3 calibration). So DPS=256 / 512
// blocks / 46 us is this decomposition's structural optimum. Reverted
// bit-for-bit to R9: PSPLIT=16, 4-wave blocks, LDS 48 KB, slabs in out0.
#define PSPLIT 16
#define DPS 256
__global__ __launch_bounds__(256) void k_corr8(
    const float* __restrict__ f1T, const float* __restrict__ f2,
    const float* __restrict__ otT, float* __restrict__ part) {
  __shared__ float smem[2 * DPS * PADK];  // 48 KB: sf1 | sot
  float* sf1 = smem;
  float* sot = smem + DPS * PADK;
  const int t = threadIdx.x;  // 0..255
  const int lane = t & 63, wid = t >> 6;
  const int n = blockIdx.z, pb = blockIdx.y;
  const int pbase = pb * DPS;
  {
    const float4* gf = (const float4*)(f1T + ((size_t)n * HW + pbase) * PADK);
    const float4* go = (const float4*)(otT + ((size_t)n * HW + pbase) * PADK);
    float4* sa = (float4*)sf1;
    float4* sb = (float4*)sot;
#pragma unroll
    for (int i = 0; i < DPS * (PADK / 4) / 256; ++i) {
      sa[t + i * 256] = gf[t + i * 256];
      sb[t + i * 256] = go[t + i * 256];
    }
  }
  __syncthreads();
  const int q = blockIdx.x * 256 + lane * 4;
  const float* f2n = f2 + (size_t)n * NCL * HW;
  float4 fq[NCL];
#pragma unroll
  for (int k = 0; k < NCL; ++k)
    fq[k] = *(const float4*)(f2n + (size_t)k * HW + q);
  float4 acc[NCL];
#pragma unroll
  for (int k = 0; k < NCL; ++k) acc[k] = make_float4(0.f, 0.f, 0.f, 0.f);
  const int plo = wid * (DPS / 4);
  const int phi = plo + (DPS / 4);
#pragma unroll 2
  for (int p = plo; p < phi; ++p) {
    const float4* r1 = (const float4*)(sf1 + p * PADK);
    float a[NCL];
    *(float4*)(a + 0) = r1[0];
    *(float4*)(a + 4) = r1[1];
    *(float4*)(a + 8) = r1[2];
    *(float4*)(a + 12) = r1[3];
    *(float4*)(a + 16) = r1[4];
    a[20] = ((const float*)r1)[20];
    float d0 = 0.f, d1 = 0.f, d2 = 0.f, d3 = 0.f;  // 4 independent chains
#pragma unroll
    for (int k = 0; k < NCL; ++k) {
      d0 = fmaf(a[k], fq[k].x, d0);
      d1 = fmaf(a[k], fq[k].y, d1);
      d2 = fmaf(a[k], fq[k].z, d2);
      d3 = fmaf(a[k], fq[k].w, d3);
    }
    float w0 = __expf(d0), w1 = __expf(d1), w2 = __expf(d2), w3 = __expf(d3);
    const float4* ro = (const float4*)(sot + p * PADK);
    float o[NCL];
    *(float4*)(o + 0) = ro[0];
    *(float4*)(o + 4) = ro[1];
    *(float4*)(o + 8) = ro[2];
    *(float4*)(o + 12) = ro[3];
    *(float4*)(o + 16) = ro[4];
    o[20] = ((const float*)ro)[20];
#pragma unroll
    for (int k = 0; k < NCL; ++k) {
      acc[k].x = fmaf(o[k], w0, acc[k].x);
      acc[k].y = fmaf(o[k], w1, acc[k].y);
      acc[k].z = fmaf(o[k], w2, acc[k].z);
      acc[k].w = fmaf(o[k], w3, acc[k].w);
    }
  }
  // 3-round ping-pong combine through the (now dead) LDS tile: one wave's
  // acc = 21*64 float4 = 5.4 KB <= 48 KB buffer.
  __syncthreads();  // all ds reads of sf1/sot done; safe to reuse smem
  float4* sbuf = (float4*)smem;
  if (wid == 1) {
#pragma unroll
    for (int c = 0; c < NCL; ++c) sbuf[c * 64 + lane] = acc[c];
  }
  __syncthreads();
  if (wid == 0) {
#pragma unroll
    for (int c = 0; c < NCL; ++c) {
      float4 v = sbuf[c * 64 + lane];
      acc[c].x += v.x; acc[c].y += v.y; acc[c].z += v.z; acc[c].w += v.w;
    }
  }
  __syncthreads();
  if (wid == 3) {
#pragma unroll
    for (int c = 0; c < NCL; ++c) sbuf[c * 64 + lane] = acc[c];
  }
  __syncthreads();
  if (wid == 2) {
#pragma unroll
    for (int c = 0; c < NCL; ++c) {
      float4 v = sbuf[c * 64 + lane];
      acc[c].x += v.x; acc[c].y += v.y; acc[c].z += v.z; acc[c].w += v.w;
    }
  }
  __syncthreads();
  if (wid == 2) {
#pragma unroll
    for (int c = 0; c < NCL; ++c) sbuf[c * 64 + lane] = acc[c];
  }
  __syncthreads();
  if (wid == 0) {
    float* po = part + ((size_t)pb * NB + n) * NCL * HW + q;
#pragma unroll
    for (int c = 0; c < NCL; ++c) {
      float4 v = sbuf[c * 64 + lane];
      v.x += acc[c].x; v.y += acc[c].y; v.z += acc[c].z; v.w += acc[c].w;
      *(float4*)(po + (size_t)c * HW) = v;
    }
  }
}

// ---------------------------------------------------------------------------
// Kernel D2: corr_out[idx] = sum over the 16 partial slabs. 672 blocks,
// fully coalesced strided reads; replaces the corr_out memset too.
__global__ __launch_bounds__(256) void k_reduce(
    const float* __restrict__ part, float* __restrict__ corr_out) {
  const int idx = blockIdx.x * 256 + threadIdx.x;  // NB*NCL*HW = 672*256
  const float* p = part + idx;
  float s = 0.f;
#pragma unroll
  for (int pb = 0; pb < PSPLIT; ++pb)
    s += p[(size_t)pb * (NB * NCL * HW)];
  corr_out[idx] = s;
}

// ---------------------------------------------------------------------------
// Kernel E (fused): per sampled row (i, n): compute the unnormalized exp-row
// straight into LDS (min/max normalization is invariant to the softmax
// denominator), bilinear tables in-block, upsample 64->128, min/max
// normalize, write >0.5 booleans as 1.0/0.0.
__global__ __launch_bounds__(256) void k_norm(
    const float* __restrict__ f1T, const float* __restrict__ f2,
    const int* __restrict__ index, float* __restrict__ out0) {
  __shared__ float row[HW];
  __shared__ float redmn[4], redmx[4];
  __shared__ float wt[128];
  __shared__ int it[128];
  const int t = threadIdx.x;
  const int i = blockIdx.x;
  const int n = blockIdx.y;
  if (t < 128) {
    double s = (double)t * (63.0 / 127.0);
    int i0 = (int)s;
    wt[t] = (float)(s - i0);
    it[t] = i0;
  }
  int p = index[i];
  p = max(0, min(p, HW - 1));
  const float* f1p = f1T + ((size_t)n * HW + p) * PADK;
  float a[NCL];
#pragma unroll
  for (int k = 0; k < NCL; ++k) a[k] = f1p[k];
  const float* f2n = f2 + (size_t)n * NCL * HW;
  for (int qc = 0; qc < 4; ++qc) {
    const int q0 = qc * 1024 + t * 4;
    float d0 = 0.f, d1 = 0.f, d2 = 0.f, d3 = 0.f;
#pragma unroll
    for (int k = 0; k < NCL; ++k) {
      float4 f = *(const float4*)(f2n + (size_t)k * HW + q0);
      d0 = fmaf(a[k], f.x, d0);
      d1 = fmaf(a[k], f.y, d1);
      d2 = fmaf(a[k], f.z, d2);
      d3 = fmaf(a[k], f.w, d3);
    }
    *(float4*)(row + q0) =
        make_float4(__expf(d0), __expf(d1), __expf(d2), __expf(d3));
  }
  __syncthreads();
  float vv[64];
  float lmn = 1e30f, lmx = -1e30f;
  for (int j = 0; j < 64; ++j) {
    int pix = t + j * 256;
    int yy = pix >> 7, xx = pix & 127;
    int y0 = it[yy], x0 = it[xx];
    float wy = wt[yy], wx = wt[xx];
    int y1 = min(y0 + 1, 63), x1 = min(x0 + 1, 63);
    float r0 = row[y0 * 64 + x0] * (1.f - wy) + row[y1 * 64 + x0] * wy;
    float r1 = row[y0 * 64 + x1] * (1.f - wy) + row[y1 * 64 + x1] * wy;
    float v = r0 * (1.f - wx) + r1 * wx;
    vv[j] = v;
    lmn = fminf(lmn, v);
    lmx = fmaxf(lmx, v);
  }
  for (int off = 32; off > 0; off >>= 1) {
    lmn = fminf(lmn, __shfl_xor(lmn, off, 64));
    lmx = fmaxf(lmx, __shfl_xor(lmx, off, 64));
  }
  const int wave = t >> 6, lane = t & 63;
  if (lane == 0) { redmn[wave] = lmn; redmx[wave] = lmx; }
  __syncthreads();
  float mn = fminf(fminf(redmn[0], redmn[1]), fminf(redmn[2], redmn[3]));
  float mx = fmaxf(fmaxf(redmx[0], redmx[1]), fmaxf(redmx[2], redmx[3]));
  float rng = mx - mn;
  float* slot = out0 + ((size_t)n * 128 + i) * (128 * 128);
  for (int j = 0; j < 64; ++j) {
    int pix = t + j * 256;
    float nrm = (vv[j] - mn) / rng;
    slot[pix] = (nrm > 0.5f) ? 1.0f : 0.0f;
  }
}

// ---------------------------------------------------------------------------
extern "C" void kernel_launch(void* const* d_in, const int* in_sizes, int n_in,
                              void* d_out, int out_size, void* d_ws,
                              size_t ws_size, hipStream_t stream) {
  (void)in_sizes; (void)n_in; (void)out_size; (void)ws_size;
  const float* feat = (const float*)d_in[0];
  const float* out  = (const float*)d_in[1];
  const float* w1   = (const float*)d_in[2];
  const float* b1   = (const float*)d_in[3];
  const float* w2   = (const float*)d_in[4];
  const float* b2   = (const float*)d_in[5];
  const int* index  = (const int*)d_in[6];

  float* ws   = (float*)d_ws;
  float* f1T  = ws;                                   // 2*4096*24 = 196608
  float* f2   = ws + 196608;                          // 2*21*4096 = 172032
  float* otT  = ws + 196608 + 172032;                 // 196608

  float* out0     = (float*)d_out;                    // 2*128*128*128
  float* corr_out = out0 + (size_t)NB * 128 * 128 * 128;  // 2*21*4096
  // partial slabs: 16 * 2 * 21 * 4096 floats = 10.8 MB, parked inside the
  // out0 region (16.8 MB) -- consumed by k_reduce before k_norm writes out0.
  float* part = out0;

  k_feat<<<dim3(HW / QT, 2), 256, 0, stream>>>(feat, w1, b1, w2, b2, f1T, f2);
  k_statsoutr<<<dim3(HW / PT, 2), 256, 0, stream>>>(f1T, f2, out, otT);
  k_corr8<<<dim3(16, PSPLIT, 2), 256, 0, stream>>>(f1T, f2, otT, part);
  k_reduce<<<dim3(672), 256, 0, stream>>>(part, corr_out);
  k_norm<<<dim3(128, 2), 256, 0, stream>>>(f1T, f2, index, out0);
}

// Round 12
// 175.491 us; speedup vs baseline: 1.1232x; 1.0718x over previous
//
#include <hip/hip_runtime.h>
#include <math.h>

#define NCL 21
#define CIN 256
#define HW 4096
#define PADK 24
#define NB 2

static __device__ __forceinline__ float fastrcp(float x) {
  return __builtin_amdgcn_rcpf(x);
}

// ---------------------------------------------------------------------------
// Kernel A: f1/f2 = 1x1 conv (w @ feat + b). f1 rows are PRE-SCALED by
// 1/sqrt(21) (all three consumers -- stats, corr, norm -- multiply the dot by
// SCALE, so fold it into f1 once). Block = 16 q x 16 c-chunks; LDS reduction.
#define QT 16
#define CCH 16
__global__ __launch_bounds__(256) void k_feat(
    const float* __restrict__ feat, const float* __restrict__ w1,
    const float* __restrict__ b1, const float* __restrict__ w2,
    const float* __restrict__ b2, float* __restrict__ f1T,
    float* __restrict__ f2) {
  const int t = threadIdx.x;
  const int qi = t & 15, ch = t >> 4;  // 16 chunks of 16 channels
  const int n = blockIdx.y;
  const int q = blockIdx.x * QT + qi;
  const int c0 = ch * CCH;
  const float* fp = feat + ((size_t)n * CIN + c0) * HW + q;
  float a1[NCL], a2[NCL];
#pragma unroll
  for (int k = 0; k < NCL; ++k) { a1[k] = 0.f; a2[k] = 0.f; }
#pragma unroll
  for (int cc = 0; cc < CCH; ++cc) {
    float v = fp[(size_t)cc * HW];
#pragma unroll
    for (int k = 0; k < NCL; ++k) {  // w reads thread-uniform -> s_load
      a1[k] = fmaf(v, w1[k * CIN + c0 + cc], a1[k]);
      a2[k] = fmaf(v, w2[k * CIN + c0 + cc], a2[k]);
    }
  }
  __shared__ float p1[CCH][QT][NCL];
  __shared__ float p2[CCH][QT][NCL];
#pragma unroll
  for (int k = 0; k < NCL; ++k) { p1[ch][qi][k] = a1[k]; p2[ch][qi][k] = a2[k]; }
  __syncthreads();
  const float SCALE = 1.0f / sqrtf(21.0f);
  for (int o = t; o < QT * NCL; o += 256) {
    int qq = o & 15, k = o >> 4;
    float s1 = b1[k], s2 = b2[k];
#pragma unroll
    for (int c = 0; c < CCH; ++c) { s1 += p1[c][qq][k]; s2 += p2[c][qq][k]; }
    int qg = blockIdx.x * QT + qq;
    f1T[((size_t)n * HW + qg) * PADK + k] = s1 * SCALE;  // pre-scaled
    f2[((size_t)n * NCL + k) * HW + qg] = s2;
  }
}

// ---------------------------------------------------------------------------
// Kernel C (fused, v4 RESTORED): per block = (8 p-rows, n), all 4096 q
// in-block, then the k_outr epilogue for the same 8 p. Law established by
// R7/R8/R10/R11: every PT=8 q=4 variant (k-group 4, k-step 2, decree-capped)
// lands VGPR >128 -> 2 waves/SIMD cliff -> ~49 us; only q=2 (float2) fits
// <=128 (R9: <46 us, total 178.2 -- the session best). Reverted bit-for-bit.
#define PT 8
__global__ __launch_bounds__(256) void k_statsoutr(
    const float* __restrict__ f1T, const float* __restrict__ f2,
    const float* __restrict__ out, float* __restrict__ otT) {
  __shared__ float srow[PT * PADK];  // 8 rows * 24 floats = 768 B
  __shared__ float red[4][PT];
  __shared__ float linv[PT];
  const int t = threadIdx.x;
  const int n = blockIdx.y;
  const int pbase = blockIdx.x * PT;
  if (t < PT * PADK / 4) {
    ((float4*)srow)[t] =
        ((const float4*)(f1T + ((size_t)n * HW + pbase) * PADK))[t];
  }
  __syncthreads();
  const float* f2n = f2 + (size_t)n * NCL * HW;
  float sums[PT];
#pragma unroll
  for (int p = 0; p < PT; ++p) sums[p] = 0.f;
  for (int qc = 0; qc < 8; ++qc) {
    const int q0 = qc * 512 + t * 2;
    float2 dp[PT];  // dot partials: 16 VGPR
#pragma unroll
    for (int p = 0; p < PT; ++p) dp[p] = make_float2(0.f, 0.f);
#pragma unroll
    for (int g = 0; g < 5; ++g) {  // k = 4g .. 4g+3
      float2 fg0 = *(const float2*)(f2n + (size_t)(4 * g + 0) * HW + q0);
      float2 fg1 = *(const float2*)(f2n + (size_t)(4 * g + 1) * HW + q0);
      float2 fg2 = *(const float2*)(f2n + (size_t)(4 * g + 2) * HW + q0);
      float2 fg3 = *(const float2*)(f2n + (size_t)(4 * g + 3) * HW + q0);
#pragma unroll
      for (int p = 0; p < PT; ++p) {
        float4 ag = *(const float4*)(srow + p * PADK + 4 * g);
        dp[p].x = fmaf(ag.x, fg0.x, dp[p].x);
        dp[p].y = fmaf(ag.x, fg0.y, dp[p].y);
        dp[p].x = fmaf(ag.y, fg1.x, dp[p].x);
        dp[p].y = fmaf(ag.y, fg1.y, dp[p].y);
        dp[p].x = fmaf(ag.z, fg2.x, dp[p].x);
        dp[p].y = fmaf(ag.z, fg2.y, dp[p].y);
        dp[p].x = fmaf(ag.w, fg3.x, dp[p].x);
        dp[p].y = fmaf(ag.w, fg3.y, dp[p].y);
      }
    }
    {  // k = 20 tail
      float2 f20 = *(const float2*)(f2n + (size_t)20 * HW + q0);
#pragma unroll
      for (int p = 0; p < PT; ++p) {
        float a20 = srow[p * PADK + 20];
        dp[p].x = fmaf(a20, f20.x, dp[p].x);
        dp[p].y = fmaf(a20, f20.y, dp[p].y);
      }
    }
#pragma unroll
    for (int p = 0; p < PT; ++p)
      sums[p] += __expf(dp[p].x) + __expf(dp[p].y);
  }
  const int wave = t >> 6, lane = t & 63;
#pragma unroll
  for (int p = 0; p < PT; ++p) {
    float s = sums[p];
    for (int off = 32; off > 0; off >>= 1) s += __shfl_xor(s, off, 64);
    if (lane == 0) red[wave][p] = s;
  }
  __syncthreads();
  if (t < PT) {
    float tot = red[0][t] + red[1][t] + red[2][t] + red[3][t];
    linv[t] = fastrcp(tot);
  }
  __syncthreads();
  // k_outr epilogue for the 8 p of this block: 8*21 = 168 outputs.
  for (int o = t; o < PT * NCL; o += 256) {
    int pl = o & 7, c = o >> 3;
    int pg = pbase + pl;
    int i = pg >> 6, j = pg & 63;
    double sy = (double)i * (127.0 / 63.0);
    double sx = (double)j * (127.0 / 63.0);
    int y0 = (int)sy, x0 = (int)sx;
    float wy = (float)(sy - y0), wx = (float)(sx - x0);
    int y1 = min(y0 + 1, 127), x1 = min(x0 + 1, 127);
    const float* src = out + ((size_t)n * NCL + c) * (128 * 128);
    float v00 = src[y0 * 128 + x0], v10 = src[y1 * 128 + x0];
    float v01 = src[y0 * 128 + x1], v11 = src[y1 * 128 + x1];
    float r0 = v00 * (1.f - wy) + v10 * wy;
    float r1 = v01 * (1.f - wy) + v11 * wy;
    float val = r0 * (1.f - wx) + r1 * wx;
    otT[((size_t)n * HW + pg) * PADK + c] = val * linv[pl];
  }
}

// ---------------------------------------------------------------------------
// Kernel D (v8, R9-proven): DPS=256 / 512 blocks = 2 blocks/CU single round.
// R10 established the Q=4 loop's true live set is ~168 unified regs (arch
// VGPR 128 + AGPR balance) -> real cap ~3 waves/SIMD; finer p-splits (1024
// blocks) leave 1.33 scheduling rounds. This is the decomposition optimum.
#define PSPLIT 16
#define DPS 256
__global__ __launch_bounds__(256) void k_corr8(
    const float* __restrict__ f1T, const float* __restrict__ f2,
    const float* __restrict__ otT, float* __restrict__ part) {
  __shared__ float smem[2 * DPS * PADK];  // 48 KB: sf1 | sot
  float* sf1 = smem;
  float* sot = smem + DPS * PADK;
  const int t = threadIdx.x;  // 0..255
  const int lane = t & 63, wid = t >> 6;
  const int n = blockIdx.z, pb = blockIdx.y;
  const int pbase = pb * DPS;
  {
    const float4* gf = (const float4*)(f1T + ((size_t)n * HW + pbase) * PADK);
    const float4* go = (const float4*)(otT + ((size_t)n * HW + pbase) * PADK);
    float4* sa = (float4*)sf1;
    float4* sb = (float4*)sot;
#pragma unroll
    for (int i = 0; i < DPS * (PADK / 4) / 256; ++i) {
      sa[t + i * 256] = gf[t + i * 256];
      sb[t + i * 256] = go[t + i * 256];
    }
  }
  __syncthreads();
  const int q = blockIdx.x * 256 + lane * 4;
  const float* f2n = f2 + (size_t)n * NCL * HW;
  float4 fq[NCL];
#pragma unroll
  for (int k = 0; k < NCL; ++k)
    fq[k] = *(const float4*)(f2n + (size_t)k * HW + q);
  float4 acc[NCL];
#pragma unroll
  for (int k = 0; k < NCL; ++k) acc[k] = make_float4(0.f, 0.f, 0.f, 0.f);
  const int plo = wid * (DPS / 4);
  const int phi = plo + (DPS / 4);
#pragma unroll 2
  for (int p = plo; p < phi; ++p) {
    const float4* r1 = (const float4*)(sf1 + p * PADK);
    float a[NCL];
    *(float4*)(a + 0) = r1[0];
    *(float4*)(a + 4) = r1[1];
    *(float4*)(a + 8) = r1[2];
    *(float4*)(a + 12) = r1[3];
    *(float4*)(a + 16) = r1[4];
    a[20] = ((const float*)r1)[20];
    float d0 = 0.f, d1 = 0.f, d2 = 0.f, d3 = 0.f;  // 4 independent chains
#pragma unroll
    for (int k = 0; k < NCL; ++k) {
      d0 = fmaf(a[k], fq[k].x, d0);
      d1 = fmaf(a[k], fq[k].y, d1);
      d2 = fmaf(a[k], fq[k].z, d2);
      d3 = fmaf(a[k], fq[k].w, d3);
    }
    float w0 = __expf(d0), w1 = __expf(d1), w2 = __expf(d2), w3 = __expf(d3);
    const float4* ro = (const float4*)(sot + p * PADK);
    float o[NCL];
    *(float4*)(o + 0) = ro[0];
    *(float4*)(o + 4) = ro[1];
    *(float4*)(o + 8) = ro[2];
    *(float4*)(o + 12) = ro[3];
    *(float4*)(o + 16) = ro[4];
    o[20] = ((const float*)ro)[20];
#pragma unroll
    for (int k = 0; k < NCL; ++k) {
      acc[k].x = fmaf(o[k], w0, acc[k].x);
      acc[k].y = fmaf(o[k], w1, acc[k].y);
      acc[k].z = fmaf(o[k], w2, acc[k].z);
      acc[k].w = fmaf(o[k], w3, acc[k].w);
    }
  }
  // 3-round ping-pong combine through the (now dead) LDS tile: one wave's
  // acc = 21*64 float4 = 5.4 KB <= 48 KB buffer.
  __syncthreads();  // all ds reads of sf1/sot done; safe to reuse smem
  float4* sbuf = (float4*)smem;
  if (wid == 1) {
#pragma unroll
    for (int c = 0; c < NCL; ++c) sbuf[c * 64 + lane] = acc[c];
  }
  __syncthreads();
  if (wid == 0) {
#pragma unroll
    for (int c = 0; c < NCL; ++c) {
      float4 v = sbuf[c * 64 + lane];
      acc[c].x += v.x; acc[c].y += v.y; acc[c].z += v.z; acc[c].w += v.w;
    }
  }
  __syncthreads();
  if (wid == 3) {
#pragma unroll
    for (int c = 0; c < NCL; ++c) sbuf[c * 64 + lane] = acc[c];
  }
  __syncthreads();
  if (wid == 2) {
#pragma unroll
    for (int c = 0; c < NCL; ++c) {
      float4 v = sbuf[c * 64 + lane];
      acc[c].x += v.x; acc[c].y += v.y; acc[c].z += v.z; acc[c].w += v.w;
    }
  }
  __syncthreads();
  if (wid == 2) {
#pragma unroll
    for (int c = 0; c < NCL; ++c) sbuf[c * 64 + lane] = acc[c];
  }
  __syncthreads();
  if (wid == 0) {
    float* po = part + ((size_t)pb * NB + n) * NCL * HW + q;
#pragma unroll
    for (int c = 0; c < NCL; ++c) {
      float4 v = sbuf[c * 64 + lane];
      v.x += acc[c].x; v.y += acc[c].y; v.z += acc[c].z; v.w += acc[c].w;
      *(float4*)(po + (size_t)c * HW) = v;
    }
  }
}

// ---------------------------------------------------------------------------
// Kernel D2: corr_out[idx] = sum over the 16 partial slabs. 672 blocks,
// fully coalesced strided reads; replaces the corr_out memset too.
__global__ __launch_bounds__(256) void k_reduce(
    const float* __restrict__ part, float* __restrict__ corr_out) {
  const int idx = blockIdx.x * 256 + threadIdx.x;  // NB*NCL*HW = 672*256
  const float* p = part + idx;
  float s = 0.f;
#pragma unroll
  for (int pb = 0; pb < PSPLIT; ++pb)
    s += p[(size_t)pb * (NB * NCL * HW)];
  corr_out[idx] = s;
}

// ---------------------------------------------------------------------------
// Kernel E (fused, v2): per sampled row (i, n). R11 analysis: at 256 threads
// this kernel ran 256 blocks = 1 block/CU x 4 waves = 1 WAVE/SIMD -- the
// worst residency in the pipeline (R2's disease), ~20-25 us of exposed
// latency for tiny work. Now 1024 threads/block (16 waves = 4 waves/SIMD,
// same 256-block grid = 1 block/CU): row compute is a single pass (1024 thr
// x 4 q = 4096), upsample 16 px/thread (vv[16]), min/max tree over 16 waves.
// Work identical; residency x4.
__global__ __launch_bounds__(1024) void k_norm(
    const float* __restrict__ f1T, const float* __restrict__ f2,
    const int* __restrict__ index, float* __restrict__ out0) {
  __shared__ float row[HW];
  __shared__ float redmn[16], redmx[16];
  __shared__ float wt[128];
  __shared__ int it[128];
  const int t = threadIdx.x;  // 0..1023
  const int i = blockIdx.x;
  const int n = blockIdx.y;
  if (t < 128) {
    double s = (double)t * (63.0 / 127.0);
    int i0 = (int)s;
    wt[t] = (float)(s - i0);
    it[t] = i0;
  }
  int p = index[i];
  p = max(0, min(p, HW - 1));
  const float* f1p = f1T + ((size_t)n * HW + p) * PADK;  // uniform -> s_load
  float a[NCL];
#pragma unroll
  for (int k = 0; k < NCL; ++k) a[k] = f1p[k];
  const float* f2n = f2 + (size_t)n * NCL * HW;
  {
    const int q0 = t * 4;  // 1024 threads x 4 = all 4096 q in one pass
    float d0 = 0.f, d1 = 0.f, d2 = 0.f, d3 = 0.f;
#pragma unroll
    for (int k = 0; k < NCL; ++k) {
      float4 f = *(const float4*)(f2n + (size_t)k * HW + q0);
      d0 = fmaf(a[k], f.x, d0);
      d1 = fmaf(a[k], f.y, d1);
      d2 = fmaf(a[k], f.z, d2);
      d3 = fmaf(a[k], f.w, d3);
    }
    *(float4*)(row + q0) =
        make_float4(__expf(d0), __expf(d1), __expf(d2), __expf(d3));
  }
  __syncthreads();
  float vv[16];
  float lmn = 1e30f, lmx = -1e30f;
#pragma unroll
  for (int j = 0; j < 16; ++j) {
    int pix = t + j * 1024;
    int yy = pix >> 7, xx = pix & 127;
    int y0 = it[yy], x0 = it[xx];
    float wy = wt[yy], wx = wt[xx];
    int y1 = min(y0 + 1, 63), x1 = min(x0 + 1, 63);
    float r0 = row[y0 * 64 + x0] * (1.f - wy) + row[y1 * 64 + x0] * wy;
    float r1 = row[y0 * 64 + x1] * (1.f - wy) + row[y1 * 64 + x1] * wy;
    float v = r0 * (1.f - wx) + r1 * wx;
    vv[j] = v;
    lmn = fminf(lmn, v);
    lmx = fmaxf(lmx, v);
  }
  for (int off = 32; off > 0; off >>= 1) {
    lmn = fminf(lmn, __shfl_xor(lmn, off, 64));
    lmx = fmaxf(lmx, __shfl_xor(lmx, off, 64));
  }
  const int wave = t >> 6, lane = t & 63;
  if (lane == 0) { redmn[wave] = lmn; redmx[wave] = lmx; }
  __syncthreads();
  float mn = redmn[0], mx = redmx[0];
#pragma unroll
  for (int w = 1; w < 16; ++w) {
    mn = fminf(mn, redmn[w]);
    mx = fmaxf(mx, redmx[w]);
  }
  float rng = mx - mn;
  float* slot = out0 + ((size_t)n * 128 + i) * (128 * 128);
#pragma unroll
  for (int j = 0; j < 16; ++j) {
    int pix = t + j * 1024;
    float nrm = (vv[j] - mn) / rng;
    slot[pix] = (nrm > 0.5f) ? 1.0f : 0.0f;
  }
}

// ---------------------------------------------------------------------------
extern "C" void kernel_launch(void* const* d_in, const int* in_sizes, int n_in,
                              void* d_out, int out_size, void* d_ws,
                              size_t ws_size, hipStream_t stream) {
  (void)in_sizes; (void)n_in; (void)out_size; (void)ws_size;
  const float* feat = (const float*)d_in[0];
  const float* out  = (const float*)d_in[1];
  const float* w1   = (const float*)d_in[2];
  const float* b1   = (const float*)d_in[3];
  const float* w2   = (const float*)d_in[4];
  const float* b2   = (const float*)d_in[5];
  const int* index  = (const int*)d_in[6];

  float* ws   = (float*)d_ws;
  float* f1T  = ws;                                   // 2*4096*24 = 196608
  float* f2   = ws + 196608;                          // 2*21*4096 = 172032
  float* otT  = ws + 196608 + 172032;                 // 196608

  float* out0     = (float*)d_out;                    // 2*128*128*128
  float* corr_out = out0 + (size_t)NB * 128 * 128 * 128;  // 2*21*4096
  // partial slabs: 16 * 2 * 21 * 4096 floats = 10.8 MB, parked inside the
  // out0 region (16.8 MB) -- consumed by k_reduce before k_norm writes out0.
  float* part = out0;

  k_feat<<<dim3(HW / QT, 2), 256, 0, stream>>>(feat, w1, b1, w2, b2, f1T, f2);
  k_statsoutr<<<dim3(HW / PT, 2), 256, 0, stream>>>(f1T, f2, out, otT);
  k_corr8<<<dim3(16, PSPLIT, 2), 256, 0, stream>>>(f1T, f2, otT, part);
  k_reduce<<<dim3(672), 256, 0, stream>>>(part, corr_out);
  k_norm<<<dim3(128, 2), 1024, 0, stream>>>(f1T, f2, index, out0);
}